// Round 1
// baseline (825.429 us; speedup 1.0000x reference)
//
#include <hip/hip_runtime.h>

// Problem constants (from reference): BATCH=256, N_BLOCKS=32, DC=2, N_QUBITS=12, DIM=4096
#define NQ        12
#define DIM       4096
#define N_BLOCKS  32
#define TOTAL     67108864   // 256*32*2*4096 elements per (re|im) plane
#define N4        16777216   // TOTAL / 4
#define LUT_ELEMS 131072     // 32 * 4096 phasors

// --- Kernel 1: build phasor LUT, lut[k*4096 + d] = (cos(0.5*phase), sin(0.5*phase))
// phase[k][d] = sum_q w[k][q] * (1 - 2*((d >> (11-q)) & 1))
__global__ void build_lut_kernel(const float* __restrict__ w, float2* __restrict__ lut) {
    int t = blockIdx.x * blockDim.x + threadIdx.x;
    if (t >= LUT_ELEMS) return;
    int k = t >> 12;            // block index 0..31
    int d = t & (DIM - 1);      // dim index 0..4095
    const float* wk = w + k * NQ;   // weights flat layout (1,32,1,12,1) -> k*12+q
    float phase = 0.f;
#pragma unroll
    for (int q = 0; q < NQ; ++q) {
        float wq = wk[q];
        phase += ((d >> (NQ - 1 - q)) & 1) ? -wq : wq;
    }
    float th = 0.5f * phase;    // U = exp(-i*th) = cos(th) - i*sin(th)
    float s, c;
    sincosf(th, &s, &c);
    lut[t] = make_float2(c, s);
}

// --- Kernel 2: streaming complex multiply, float4 everywhere.
// out_re = c*re + s*im ; out_im = c*im - s*re
__global__ void apply_lut_kernel(const float4* __restrict__ re, const float4* __restrict__ im,
                                 const float2* __restrict__ lut,
                                 float4* __restrict__ outr, float4* __restrict__ outi) {
    int i = blockIdx.x * blockDim.x + threadIdx.x;
    if (i >= N4) return;
    int r  = i >> 10;           // row index = (b*32 + k)*2 + c  (1024 float4 per 4096-dim row)
    int k  = (r >> 1) & (N_BLOCKS - 1);
    int d4 = i & 1023;          // which group of 4 dims within the row
    // 4 consecutive float2 phasors = 32B, 32B-aligned -> two float4 loads
    const float4* l4 = (const float4*)(lut + (k << 12) + (d4 << 2));
    float4 cs01 = l4[0];        // c0,s0,c1,s1
    float4 cs23 = l4[1];        // c2,s2,c3,s3
    float4 a = re[i];
    float4 b = im[i];
    float4 orv, oiv;
    orv.x = cs01.x * a.x + cs01.y * b.x;  oiv.x = cs01.x * b.x - cs01.y * a.x;
    orv.y = cs01.z * a.y + cs01.w * b.y;  oiv.y = cs01.z * b.y - cs01.w * a.y;
    orv.z = cs23.x * a.z + cs23.y * b.z;  oiv.z = cs23.x * b.z - cs23.y * a.z;
    orv.w = cs23.z * a.w + cs23.w * b.w;  oiv.w = cs23.z * b.w - cs23.w * a.w;
    outr[i] = orv;
    outi[i] = oiv;
}

// --- Fallback (only if ws_size < 1MB): compute phases inline.
// The 4 dims a thread handles share the phase contribution of qubits 0..9;
// only w[10], w[11] signs differ across the 4 lanes -> 4 sincos per thread.
__global__ void apply_inline_kernel(const float4* __restrict__ re, const float4* __restrict__ im,
                                    const float* __restrict__ w,
                                    float4* __restrict__ outr, float4* __restrict__ outi) {
    int i = blockIdx.x * blockDim.x + threadIdx.x;
    if (i >= N4) return;
    int r  = i >> 10;
    int k  = (r >> 1) & (N_BLOCKS - 1);
    int d4 = i & 1023;
    int d0 = d4 << 2;           // low 2 bits are 0
    const float* wk = w + k * NQ;
    float phase_hi = 0.f;
#pragma unroll
    for (int q = 0; q < 10; ++q) {
        float wq = wk[q];
        phase_hi += ((d0 >> (NQ - 1 - q)) & 1) ? -wq : wq;
    }
    float w10 = wk[10], w11 = wk[11];
    float p0 = phase_hi + w10 + w11;   // j=0: bit1=0, bit0=0
    float p1 = phase_hi + w10 - w11;   // j=1
    float p2 = phase_hi - w10 + w11;   // j=2
    float p3 = phase_hi - w10 - w11;   // j=3
    float c0, s0, c1, s1, c2, s2, c3, s3;
    __sincosf(0.5f * p0, &s0, &c0);
    __sincosf(0.5f * p1, &s1, &c1);
    __sincosf(0.5f * p2, &s2, &c2);
    __sincosf(0.5f * p3, &s3, &c3);
    float4 a = re[i];
    float4 b = im[i];
    float4 orv, oiv;
    orv.x = c0 * a.x + s0 * b.x;  oiv.x = c0 * b.x - s0 * a.x;
    orv.y = c1 * a.y + s1 * b.y;  oiv.y = c1 * b.y - s1 * a.y;
    orv.z = c2 * a.z + s2 * b.z;  oiv.z = c2 * b.z - s2 * a.z;
    orv.w = c3 * a.w + s3 * b.w;  oiv.w = c3 * b.w - s3 * a.w;
    outr[i] = orv;
    outi[i] = oiv;
}

extern "C" void kernel_launch(void* const* d_in, const int* in_sizes, int n_in,
                              void* d_out, int out_size, void* d_ws, size_t ws_size,
                              hipStream_t stream) {
    const float4* re = (const float4*)d_in[0];
    const float4* im = (const float4*)d_in[1];
    const float*  w  = (const float*)d_in[2];
    float4* outr = (float4*)d_out;
    float4* outi = outr + N4;   // second plane: imag

    const int threads = 256;
    if (ws_size >= LUT_ELEMS * sizeof(float2)) {
        float2* lut = (float2*)d_ws;
        build_lut_kernel<<<(LUT_ELEMS + threads - 1) / threads, threads, 0, stream>>>(w, lut);
        apply_lut_kernel<<<N4 / threads, threads, 0, stream>>>(re, im, lut, outr, outi);
    } else {
        apply_inline_kernel<<<N4 / threads, threads, 0, stream>>>(re, im, w, outr, outi);
    }
}

// Round 2
// 800.348 us; speedup vs baseline: 1.0313x; 1.0313x over previous
//
#include <hip/hip_runtime.h>

// Rz phase layer: out = exp(-0.5i*phase[k][d]) * (re + i*im)
// BATCH=256, N_BLOCKS=32, DC=2, N_QUBITS=12, DIM=4096
#define NQ     12
#define DIM    4096
#define TOTAL  67108864   // elements per plane (re / im)
#define N4     16777216   // TOTAL / 4

typedef float v4f __attribute__((ext_vector_type(4)));

// Single fused streaming kernel. One float4 (4 consecutive dims) per thread.
// The 4 dims share qubits 0..9; only w[10], w[11] signs differ.
// out_re = c*re + s*im ; out_im = c*im - s*re   (c=cos(th), s=sin(th), th=0.5*phase)
__global__ __launch_bounds__(256) void rz_fused_kernel(
        const v4f* __restrict__ re, const v4f* __restrict__ im,
        const float* __restrict__ w,
        v4f* __restrict__ outr, v4f* __restrict__ outi) {
    int i = blockIdx.x * blockDim.x + threadIdx.x;
    if (i >= N4) return;
    int r  = i >> 10;                 // row = (b*32 + k)*2 + c ; 1024 float4 per row
    int k  = (r >> 1) & 31;           // circuit block index (wave-uniform)
    int d4 = i & 1023;
    int d0 = d4 << 2;                 // first dim of this thread's group of 4

    const float* wk = w + k * NQ;     // weights flat (1,32,1,12,1) -> k*12+q
    float h = 0.f;
#pragma unroll
    for (int q = 0; q < 10; ++q) {
        float wq = wk[q];
        h += ((d0 >> (NQ - 1 - q)) & 1) ? -wq : wq;
    }
    float w10 = wk[10], w11 = wk[11];
    // j = 0..3 : qubit10 bit = (j>>1)&1, qubit11 bit = j&1 ; sign = +1 if bit==0
    float c0, s0, c1, s1, c2, s2, c3, s3;
    __sincosf(0.5f * (h + w10 + w11), &s0, &c0);
    __sincosf(0.5f * (h + w10 - w11), &s1, &c1);
    __sincosf(0.5f * (h - w10 + w11), &s2, &c2);
    __sincosf(0.5f * (h - w10 - w11), &s3, &c3);

    v4f a = __builtin_nontemporal_load(re + i);
    v4f b = __builtin_nontemporal_load(im + i);
    v4f orv, oiv;
    orv.x = c0 * a.x + s0 * b.x;  oiv.x = c0 * b.x - s0 * a.x;
    orv.y = c1 * a.y + s1 * b.y;  oiv.y = c1 * b.y - s1 * a.y;
    orv.z = c2 * a.z + s2 * b.z;  oiv.z = c2 * b.z - s2 * a.z;
    orv.w = c3 * a.w + s3 * b.w;  oiv.w = c3 * b.w - s3 * a.w;
    __builtin_nontemporal_store(orv, outr + i);
    __builtin_nontemporal_store(oiv, outi + i);
}

extern "C" void kernel_launch(void* const* d_in, const int* in_sizes, int n_in,
                              void* d_out, int out_size, void* d_ws, size_t ws_size,
                              hipStream_t stream) {
    const v4f* re = (const v4f*)d_in[0];
    const v4f* im = (const v4f*)d_in[1];
    const float* w = (const float*)d_in[2];
    v4f* outr = (v4f*)d_out;
    v4f* outi = outr + N4;            // plane 1: imag

    const int threads = 256;
    rz_fused_kernel<<<N4 / threads, threads, 0, stream>>>(re, im, w, outr, outi);
}